// Round 1
// baseline (124.097 us; speedup 1.0000x reference)
//
#include <hip/hip_runtime.h>
#include <hip/hip_bf16.h>
#include <stdint.h>

// Problem constants
#define B_ 4
#define L_ 1024
#define D_ 768
#define H_ 12
#define HD_ 64
#define M_ 4096     // B*L
#define N3_ 2304    // 3*D

typedef float f32x4 __attribute__((ext_vector_type(4)));
typedef float f32x4v __attribute__((ext_vector_type(4)));
typedef short bf16x8 __attribute__((ext_vector_type(8)));
typedef unsigned short u16;
typedef u16 u16x8 __attribute__((ext_vector_type(8)));
typedef u16 u16x4 __attribute__((ext_vector_type(4)));

#define AS3 __attribute__((address_space(3)))
#define AS1 __attribute__((address_space(1)))

__device__ __forceinline__ void gll16(const void* g, void* l) {
  __builtin_amdgcn_global_load_lds((const AS1 void*)g, (AS3 void*)l, 16, 0, 0);
}

// fp32 -> bf16 round-to-nearest-even (finite data)
__device__ __forceinline__ u16 f2bf(float f) {
  uint32_t u = __builtin_bit_cast(uint32_t, f);
  u += 0x7fffu + ((u >> 16) & 1u);
  return (u16)(u >> 16);
}

// ---------------- conversion kernel (fp32 -> bf16, 4 elems/thread) ----------
__global__ void k_cvt(const float* __restrict__ in, u16* __restrict__ out, int n4) {
  int i = blockIdx.x * 256 + threadIdx.x;
  if (i < n4) {
    f32x4v v = ((const f32x4v*)in)[i];
    u16x4 o;
    o.x = f2bf(v.x); o.y = f2bf(v.y); o.z = f2bf(v.z); o.w = f2bf(v.w);
    ((u16x4*)out)[i] = o;
  }
}

// ---------------- GEMM1: qkv = x @ w_in^T + b_in -> Q,K,V bf16 [B,H,L,64] ----
__global__ __launch_bounds__(256) void k_gemm_qkv(
    const u16* __restrict__ Xb, const u16* __restrict__ Wb,
    const float* __restrict__ b_in,
    u16* __restrict__ gQ, u16* __restrict__ gK, u16* __restrict__ gV) {
  __shared__ u16 As[128 * 64];
  __shared__ u16 Bs[128 * 64];
  const int tid = threadIdx.x;
  const int lane = tid & 63;
  const int w = tid >> 6;
  const int wm = (w >> 1) * 64;
  const int wn = (w & 1) * 64;
  const int lr = lane & 15;
  const int lg = lane >> 4;
  const int m0 = blockIdx.x * 128;
  const int n0 = blockIdx.y * 128;

  f32x4 acc[4][4];
#pragma unroll
  for (int i = 0; i < 4; ++i)
#pragma unroll
    for (int j = 0; j < 4; ++j) acc[i][j] = (f32x4){0.f, 0.f, 0.f, 0.f};

  for (int kt = 0; kt < 12; ++kt) {
    __syncthreads();
#pragma unroll
    for (int i = 0; i < 4; ++i) {
      int seg = i * 256 + tid;
      int row = seg >> 3;
      int sl = (seg & 7) ^ (row & 7);
      gll16(Xb + (size_t)(m0 + row) * 768 + kt * 64 + sl * 8, (char*)As + seg * 16);
      gll16(Wb + (size_t)(n0 + row) * 768 + kt * 64 + sl * 8, (char*)Bs + seg * 16);
    }
    __syncthreads();
#pragma unroll
    for (int kh = 0; kh < 2; ++kh) {
      bf16x8 af[4], bfr[4];
#pragma unroll
      for (int t = 0; t < 4; ++t) {
        int ra = wm + t * 16 + lr;
        af[t] = *(const bf16x8*)((const char*)As + ra * 128 +
                                 ((kh * 64 + lg * 16) ^ ((ra & 7) << 4)));
        int rb = wn + t * 16 + lr;
        bfr[t] = *(const bf16x8*)((const char*)Bs + rb * 128 +
                                  ((kh * 64 + lg * 16) ^ ((rb & 7) << 4)));
      }
#pragma unroll
      for (int mi = 0; mi < 4; ++mi)
#pragma unroll
        for (int ni = 0; ni < 4; ++ni)
          acc[mi][ni] = __builtin_amdgcn_mfma_f32_16x16x32_bf16(
              af[mi], bfr[ni], acc[mi][ni], 0, 0, 0);
    }
  }
  // epilogue: +b_in, scale q, scatter to [B,H,L,64] bf16
  const int sec = blockIdx.y / 6;  // 0=q,1=k,2=v
  u16* dst = sec == 0 ? gQ : (sec == 1 ? gK : gV);
  const float scale = sec == 0 ? 0.125f : 1.0f;
#pragma unroll
  for (int ni = 0; ni < 4; ++ni) {
    int e = n0 + wn + ni * 16 + lr;  // 0..2303
    float bias = b_in[e];
    int es = e - sec * 768;
    int h = es >> 6, d = es & 63;
#pragma unroll
    for (int mi = 0; mi < 4; ++mi) {
#pragma unroll
      for (int j = 0; j < 4; ++j) {
        int m = m0 + wm + mi * 16 + lg * 4 + j;
        int bb = m >> 10, lq = m & 1023;
        float vv = (acc[mi][ni][j] + bias) * scale;
        dst[(size_t)((bb * 12 + h) * 1024 + lq) * 64 + d] = f2bf(vv);
      }
    }
  }
}

// ---------------- V transpose: [B,H,L,64] -> [B,H,64,L] ---------------------
__global__ __launch_bounds__(256) void k_transpose(const u16* __restrict__ V,
                                                   u16* __restrict__ Vt) {
  __shared__ u16 t[64][66];
  const int tid = threadIdx.x;
  const int bh = blockIdx.x >> 4;
  const int kv0 = (blockIdx.x & 15) * 64;
  {
    int r = tid >> 2, c0 = (tid & 3) * 16;
    const u16* src = V + (size_t)(bh * 1024 + kv0 + r) * 64 + c0;
#pragma unroll
    for (int p = 0; p < 2; ++p) {
      u16x8 x = *(const u16x8*)(src + p * 8);
#pragma unroll
      for (int e = 0; e < 8; ++e) t[r][c0 + p * 8 + e] = x[e];
    }
  }
  __syncthreads();
  {
    int d = tid >> 2, k0 = (tid & 3) * 16;
    u16* dst = Vt + (size_t)(bh * 64 + d) * 1024 + kv0 + k0;
#pragma unroll
    for (int p = 0; p < 2; ++p) {
      u16x8 o;
#pragma unroll
      for (int e = 0; e < 8; ++e) o[e] = t[k0 + p * 8 + e][d];
      *(u16x8*)(dst + p * 8) = o;
    }
  }
}

// ---------------- fused flash attention ------------------------------------
__global__ __launch_bounds__(256) void k_attn(
    const u16* __restrict__ gQ, const u16* __restrict__ gK,
    const u16* __restrict__ gVt, const float* __restrict__ gBias,
    u16* __restrict__ gO) {
  __shared__ u16 Ks[64 * 64];
  __shared__ u16 Vs[64 * 64];
  __shared__ u16 Pl[4][16 * 64];
  const int tid = threadIdx.x;
  const int lane = tid & 63;
  const int w = tid >> 6;
  const int lr = lane & 15;
  const int lg = lane >> 4;
  const int bh = blockIdx.x >> 4;
  const int q0 = (blockIdx.x & 15) * 64;
  const int qr = q0 + w * 16;  // wave's q-row base within L

  // Q fragments held in registers (q pre-scaled by 1/8 in GEMM1)
  bf16x8 qa[2];
#pragma unroll
  for (int kh = 0; kh < 2; ++kh)
    qa[kh] = *(const bf16x8*)(gQ + (size_t)(bh * 1024 + qr + lr) * 64 + kh * 32 + lg * 8);

  f32x4 oacc[4];
#pragma unroll
  for (int dt = 0; dt < 4; ++dt) oacc[dt] = (f32x4){0.f, 0.f, 0.f, 0.f};
  float mrow[4] = {-1e30f, -1e30f, -1e30f, -1e30f};
  float lrow[4] = {0.f, 0.f, 0.f, 0.f};

  for (int kv0 = 0; kv0 < 1024; kv0 += 64) {
    __syncthreads();
#pragma unroll
    for (int i = 0; i < 2; ++i) {
      int seg = i * 256 + tid;
      int row = seg >> 3;
      int sl = (seg & 7) ^ (row & 7);
      gll16(gK + (size_t)(bh * 1024 + kv0 + row) * 64 + sl * 8, (char*)Ks + seg * 16);
      gll16(gVt + (size_t)(bh * 64 + row) * 1024 + kv0 + sl * 8, (char*)Vs + seg * 16);
    }
    __syncthreads();

    // S = Q K^T  (16 q-rows x 64 kv per wave)
    f32x4 s[4];
#pragma unroll
    for (int ni = 0; ni < 4; ++ni) s[ni] = (f32x4){0.f, 0.f, 0.f, 0.f};
#pragma unroll
    for (int kh = 0; kh < 2; ++kh) {
#pragma unroll
      for (int ni = 0; ni < 4; ++ni) {
        int rb = ni * 16 + lr;
        bf16x8 kb = *(const bf16x8*)((const char*)Ks + rb * 128 +
                                     ((kh * 64 + lg * 16) ^ ((rb & 7) << 4)));
        s[ni] = __builtin_amdgcn_mfma_f32_16x16x32_bf16(qa[kh], kb, s[ni], 0, 0, 0);
      }
    }
    // + bias (fp32)
    const float* bp = gBias + (size_t)(bh * 1024 + qr) * 1024 + kv0;
#pragma unroll
    for (int ni = 0; ni < 4; ++ni)
#pragma unroll
      for (int j = 0; j < 4; ++j)
        s[ni][j] += bp[(size_t)(lg * 4 + j) * 1024 + ni * 16 + lr];

    // online softmax per q-row
#pragma unroll
    for (int j = 0; j < 4; ++j) {
      float vm = fmaxf(fmaxf(s[0][j], s[1][j]), fmaxf(s[2][j], s[3][j]));
      vm = fmaxf(vm, __shfl_xor(vm, 1));
      vm = fmaxf(vm, __shfl_xor(vm, 2));
      vm = fmaxf(vm, __shfl_xor(vm, 4));
      vm = fmaxf(vm, __shfl_xor(vm, 8));
      float mnew = fmaxf(mrow[j], vm);
      float al = __expf(mrow[j] - mnew);
      mrow[j] = mnew;
      float rs = 0.f;
#pragma unroll
      for (int ni = 0; ni < 4; ++ni) {
        float p = __expf(s[ni][j] - mnew);
        s[ni][j] = p;
        rs += p;
      }
      rs += __shfl_xor(rs, 1);
      rs += __shfl_xor(rs, 2);
      rs += __shfl_xor(rs, 4);
      rs += __shfl_xor(rs, 8);
      lrow[j] = lrow[j] * al + rs;
#pragma unroll
      for (int dt = 0; dt < 4; ++dt) oacc[dt][j] *= al;
    }

    // P -> per-wave LDS (swizzled), then PV
    u16* pw = Pl[w];
#pragma unroll
    for (int ni = 0; ni < 4; ++ni)
#pragma unroll
      for (int j = 0; j < 4; ++j) {
        int row = lg * 4 + j;
        int bc = (ni * 16 + lr) * 2;
        *(u16*)((char*)pw + row * 128 + (bc ^ ((row & 7) << 4))) = f2bf(s[ni][j]);
      }
#pragma unroll
    for (int kh = 0; kh < 2; ++kh) {
      bf16x8 pa = *(const bf16x8*)((const char*)pw + lr * 128 +
                                   ((kh * 64 + lg * 16) ^ ((lr & 7) << 4)));
#pragma unroll
      for (int dt = 0; dt < 4; ++dt) {
        int rv = dt * 16 + lr;
        bf16x8 vb = *(const bf16x8*)((const char*)Vs + rv * 128 +
                                     ((kh * 64 + lg * 16) ^ ((rv & 7) << 4)));
        oacc[dt] = __builtin_amdgcn_mfma_f32_16x16x32_bf16(pa, vb, oacc[dt], 0, 0, 0);
      }
    }
  }

  // normalize + store O bf16 [B,L,D]
  const int bg = bh / 12, h = bh % 12;
#pragma unroll
  for (int j = 0; j < 4; ++j) {
    float inv = 1.0f / lrow[j];
    int row = qr + lg * 4 + j;
#pragma unroll
    for (int dt = 0; dt < 4; ++dt) {
      gO[(size_t)(bg * 1024 + row) * 768 + h * 64 + dt * 16 + lr] =
          f2bf(oacc[dt][j] * inv);
    }
  }
}

// ---------------- GEMM2: out = O @ w_out^T + b_out (fp32 out) ---------------
__global__ __launch_bounds__(256) void k_gemm_out(
    const u16* __restrict__ Ob, const u16* __restrict__ Wb,
    const float* __restrict__ b_out, float* __restrict__ out) {
  __shared__ u16 As[128 * 64];
  __shared__ u16 Bs[128 * 64];
  const int tid = threadIdx.x;
  const int lane = tid & 63;
  const int w = tid >> 6;
  const int wm = (w >> 1) * 64;
  const int wn = (w & 1) * 64;
  const int lr = lane & 15;
  const int lg = lane >> 4;
  const int m0 = blockIdx.x * 128;
  const int n0 = blockIdx.y * 128;

  f32x4 acc[4][4];
#pragma unroll
  for (int i = 0; i < 4; ++i)
#pragma unroll
    for (int j = 0; j < 4; ++j) acc[i][j] = (f32x4){0.f, 0.f, 0.f, 0.f};

  for (int kt = 0; kt < 12; ++kt) {
    __syncthreads();
#pragma unroll
    for (int i = 0; i < 4; ++i) {
      int seg = i * 256 + tid;
      int row = seg >> 3;
      int sl = (seg & 7) ^ (row & 7);
      gll16(Ob + (size_t)(m0 + row) * 768 + kt * 64 + sl * 8, (char*)As + seg * 16);
      gll16(Wb + (size_t)(n0 + row) * 768 + kt * 64 + sl * 8, (char*)Bs + seg * 16);
    }
    __syncthreads();
#pragma unroll
    for (int kh = 0; kh < 2; ++kh) {
      bf16x8 af[4], bfr[4];
#pragma unroll
      for (int t = 0; t < 4; ++t) {
        int ra = wm + t * 16 + lr;
        af[t] = *(const bf16x8*)((const char*)As + ra * 128 +
                                 ((kh * 64 + lg * 16) ^ ((ra & 7) << 4)));
        int rb = wn + t * 16 + lr;
        bfr[t] = *(const bf16x8*)((const char*)Bs + rb * 128 +
                                  ((kh * 64 + lg * 16) ^ ((rb & 7) << 4)));
      }
#pragma unroll
      for (int mi = 0; mi < 4; ++mi)
#pragma unroll
        for (int ni = 0; ni < 4; ++ni)
          acc[mi][ni] = __builtin_amdgcn_mfma_f32_16x16x32_bf16(
              af[mi], bfr[ni], acc[mi][ni], 0, 0, 0);
    }
  }
#pragma unroll
  for (int ni = 0; ni < 4; ++ni) {
    int n = n0 + wn + ni * 16 + lr;
    float bias = b_out[n];
#pragma unroll
    for (int mi = 0; mi < 4; ++mi) {
#pragma unroll
      for (int j = 0; j < 4; ++j) {
        int m = m0 + wm + mi * 16 + lg * 4 + j;
        out[(size_t)m * 768 + n] = acc[mi][ni][j] + bias;
      }
    }
  }
}

extern "C" void kernel_launch(void* const* d_in, const int* in_sizes, int n_in,
                              void* d_out, int out_size, void* d_ws, size_t ws_size,
                              hipStream_t stream) {
  const float* x = (const float*)d_in[0];
  const float* attn_bias = (const float*)d_in[1];
  const float* w_in = (const float*)d_in[2];
  const float* b_in = (const float*)d_in[3];
  const float* w_out = (const float*)d_in[4];
  const float* b_out = (const float*)d_in[5];
  float* out = (float*)d_out;

  char* ws = (char*)d_ws;
  size_t off = 0;
  u16* xb = (u16*)(ws + off);  off += (size_t)M_ * D_ * 2;        // 6291456
  u16* wib = (u16*)(ws + off); off += (size_t)N3_ * D_ * 2;       // 3538944
  u16* wob = (u16*)(ws + off); off += (size_t)D_ * D_ * 2;        // 1179648
  u16* q = (u16*)(ws + off);   off += (size_t)48 * 1024 * 64 * 2; // 6291456
  u16* k = (u16*)(ws + off);   off += (size_t)48 * 1024 * 64 * 2;
  u16* v = (u16*)(ws + off);   off += (size_t)48 * 1024 * 64 * 2;
  u16* vt = (u16*)(ws + off);  off += (size_t)48 * 1024 * 64 * 2;
  u16* ob = (u16*)(ws + off);  off += (size_t)M_ * D_ * 2;

  k_cvt<<<3072, 256, 0, stream>>>(x, xb, (M_ * D_) / 4);
  k_cvt<<<1728, 256, 0, stream>>>(w_in, wib, (N3_ * D_) / 4);
  k_cvt<<<576, 256, 0, stream>>>(w_out, wob, (D_ * D_) / 4);
  k_gemm_qkv<<<dim3(32, 18), 256, 0, stream>>>(xb, wib, b_in, q, k, v);
  k_transpose<<<768, 256, 0, stream>>>(v, vt);
  k_attn<<<768, 256, 0, stream>>>(q, k, vt, attn_bias, ob);
  k_gemm_out<<<dim3(32, 6), 256, 0, stream>>>(ob, wob, b_out, out);
}